// Round 5
// baseline (63.463 us; speedup 1.0000x reference)
//
#include <hip/hip_runtime.h>
#include <cstdint>

#define BB 8
#define NN 2048
#define CC 64
#define TI 64            // i-rows per block in k2 (4 waves x 16)
#define JSPLIT 2
#define KRANGE (NN / JSPLIT)   // 1024
#define JCH 128                // j-chunk staged in LDS
#define NCH (KRANGE / JCH)     // 8 chunks

typedef __attribute__((ext_vector_type(8))) __bf16 bf16x8;
typedef __attribute__((ext_vector_type(4))) float f32x4;
typedef __attribute__((ext_vector_type(4))) unsigned int u32x4;
typedef __attribute__((ext_vector_type(4))) int i32x4;

// ws layout (in floats):
static const size_t WS_H   = 0;                                  // B*N*C
static const size_t WS_E1  = WS_H  + (size_t)BB*NN*CC;           // B*N
static const size_t WS_E2  = WS_E1 + (size_t)BB*NN;              // B*N
static const size_t WS_HT  = WS_E2 + (size_t)BB*NN;              // hiT+loT bf16
static const size_t WS_ACC = WS_HT + (size_t)BB*CC*NN;           // JSPLIT*B*N*C floats
static const size_t WS_Z   = WS_ACC + (size_t)JSPLIT*BB*NN*CC;   // JSPLIT*B*N

// async global->LDS, 16B and 4B widths; LDS dest = wave-uniform base + lane*width
#define GL16(g, l) __builtin_amdgcn_global_load_lds( \
    (const __attribute__((address_space(1))) void*)(g), \
    (__attribute__((address_space(3))) void*)(uint32_t)(uintptr_t)(l), 16, 0, 0)
#define GL4(g, l) __builtin_amdgcn_global_load_lds( \
    (const __attribute__((address_space(1))) void*)(g), \
    (__attribute__((address_space(3))) void*)(uint32_t)(uintptr_t)(l), 4, 0, 0)
#define WAIT18() asm volatile("s_waitcnt vmcnt(18)" ::: "memory")
#define WAIT0()  asm volatile("s_waitcnt vmcnt(0)" ::: "memory")
#define BAR()    __builtin_amdgcn_s_barrier()

// ---------------- Kernel 1: h = inp @ W ; e1 = h@a1 ; e2 = h@a2 ----------------
__global__ __launch_bounds__(256) void k1_proj(const float* __restrict__ inp,
        const float* __restrict__ Wm, const float* __restrict__ av,
        float* __restrict__ h, float* __restrict__ e1, float* __restrict__ e2) {
    __shared__ float inp_lds[256];
    int t = threadIdx.x;
    size_t base = (size_t)blockIdx.x * 256;
    inp_lds[t] = inp[base + t];
    __syncthreads();
    int r = t >> 6;
    int c = t & 63;
    const float* irow = &inp_lds[r * 64];
    float acc = 0.f;
    #pragma unroll
    for (int k = 0; k < 64; k++) acc = fmaf(irow[k], Wm[k * 64 + c], acc);
    size_t row = (size_t)blockIdx.x * 4 + r;
    h[row * 64 + c] = acc;
    float v1 = acc * av[c];
    float v2 = acc * av[64 + c];
    #pragma unroll
    for (int o = 32; o > 0; o >>= 1) {
        v1 += __shfl_down(v1, o);
        v2 += __shfl_down(v2, o);
    }
    if (c == 0) { e1[row] = v1; e2[row] = v2; }
}

// ---------------- Kernel 1b: transpose h -> bf16 hi/lo, layout [b][c][n] ----------------
__global__ __launch_bounds__(256) void k1b_transpose(const float* __restrict__ h,
        unsigned short* __restrict__ hiT, unsigned short* __restrict__ loT) {
    __shared__ float tile[64][65];
    int t = threadIdx.x;
    int b = blockIdx.x >> 5;           // N/64 = 32 tiles
    int i0 = (blockIdx.x & 31) * 64;
    const float* hb = h + ((size_t)b * NN + i0) * CC;
    #pragma unroll
    for (int q = 0; q < 16; q++) {
        int idx = q * 256 + t;
        tile[idx >> 6][idx & 63] = hb[idx];
    }
    __syncthreads();
    int c = t & 63;
    int rgrp = t >> 6;           // 4 groups of 16 rows
    unsigned int uh[8], ul[8];
    #pragma unroll
    for (int p = 0; p < 8; p++) {
        unsigned int pack_h = 0, pack_l = 0;
        #pragma unroll
        for (int s = 0; s < 2; s++) {
            float v = tile[rgrp * 16 + p * 2 + s][c];
            __bf16 bh = (__bf16)v;
            float fh = (float)bh;
            __bf16 bl = (__bf16)(v - fh);
            unsigned int ubh = (unsigned int)__builtin_bit_cast(unsigned short, bh);
            unsigned int ubl = (unsigned int)__builtin_bit_cast(unsigned short, bl);
            pack_h |= ubh << (16 * s);
            pack_l |= ubl << (16 * s);
        }
        uh[p] = pack_h; ul[p] = pack_l;
    }
    size_t off = ((size_t)b * 64 + c) * NN + i0 + rgrp * 16;   // in ushorts
    u32x4* dh = (u32x4*)(hiT + off);
    u32x4* dl = (u32x4*)(loT + off);
    dh[0] = u32x4{uh[0], uh[1], uh[2], uh[3]};
    dh[1] = u32x4{uh[4], uh[5], uh[6], uh[7]};
    dl[0] = u32x4{ul[0], ul[1], ul[2], ul[3]};
    dl[1] = u32x4{ul[4], ul[5], ul[6], ul[7]};
}

// ---------------- Kernel 2: MFMA attention, async double-buffered pipeline ----------------
// grid: 512. Decode b = bid & 7 so each batch's 64 blocks land on one XCD (%8 heuristic):
// h working set (hiT[b]+loT[b] = 512 KB) stays L2-resident per XCD instead of re-pulled
// over the fabric by all 512 blocks.
__global__ __launch_bounds__(256) void k2_mfma(const int* __restrict__ adj,
        const unsigned short* __restrict__ hiT, const unsigned short* __restrict__ loT,
        const float* __restrict__ e1, const float* __restrict__ e2,
        float* __restrict__ accp, float* __restrict__ zp) {
    __shared__ __align__(16) char smem[2 * 32768 + 2 * 512];
    char* hi0 = smem;              // each 16 KB: 64 rows x 256B (128 bf16), swizzled
    char* lo0 = smem + 16384;
    char* hi1 = smem + 32768;
    char* lo1 = smem + 49152;
    char* e2L0 = smem + 65536;     // 512 B each
    char* e2L1 = smem + 66048;

    int bid = blockIdx.x;
    int b    = bid & 7;
    int rest = bid >> 3;
    int s    = rest & (JSPLIT - 1);
    int tile = rest >> 1;          // 0..31
    int i0 = tile * TI;
    int jbase = s * KRANGE;

    int t = threadIdx.x;
    int w = t >> 6;
    int l = t & 63;
    int col = l & 15;
    int kg  = l >> 4;       // k-group 0..3

    // staging geometry: wave w covers granules [w*512, w*512+512) of 2048
    int wlo = (w >> 1);               // waves 2,3 stage loT
    int cw  = (w & 1) * 32;           // base channel row
    int l4  = l >> 4;
    int sl  = l & 15;
    int wq_off = (w & 1) * 8192;      // byte offset within the 16KB half

    const int* adjrow = adj + ((size_t)b * NN + i0 + w * 16 + col) * NN;
    float e1v = e1[(size_t)b * NN + i0 + w * 16 + col];
    const float* e2b = e2 + (size_t)b * NN;
    const unsigned short* hiTb = hiT + (size_t)b * 64 * NN;
    const unsigned short* loTb = loT + (size_t)b * 64 * NN;
    const unsigned short* sTb = wlo ? loTb : hiTb;

    f32x4 acc[4];
    #pragma unroll
    for (int n = 0; n < 4; n++) acc[n] = f32x4{0.f, 0.f, 0.f, 0.f};
    f32x4 accZ = f32x4{0.f, 0.f, 0.f, 0.f};

    __bf16 onev = (__bf16)1.0f, zerov = (__bf16)0.0f;
    bf16x8 onesf;
    #pragma unroll
    for (int i = 0; i < 8; i++) onesf[i] = (col == 0) ? onev : zerov;

    i32x4 aA[8], aB[8];

#define STAGE(jcN, B) { \
    int j0s = jbase + (jcN) * JCH; \
    char* lb = (wlo ? ((B) ? lo1 : lo0) : ((B) ? hi1 : hi0)) + wq_off; \
    _Pragma("unroll") \
    for (int q = 0; q < 8; q++) { \
        int c = cw + q * 4 + l4; \
        const unsigned short* src = sTb + (size_t)c * NN + j0s + ((sl ^ (c & 7)) << 3); \
        GL16(src, lb + q * 1024); \
    } \
    GL4(e2b + j0s + l, ((B) ? e2L1 : e2L0)); \
    GL4(e2b + j0s + 64 + l, ((B) ? e2L1 : e2L0) + 256); \
}

// adj is use-once: non-temporal loads keep it from evicting the hot h set in L2
#define ADJP(jcN, arr) { \
    int j0a = jbase + (jcN) * JCH; \
    _Pragma("unroll") \
    for (int ks = 0; ks < 4; ks++) { \
        const i32x4* ap = (const i32x4*)(adjrow + j0a + ks * 32 + kg * 8); \
        arr[2 * ks]     = __builtin_nontemporal_load(ap); \
        arr[2 * ks + 1] = __builtin_nontemporal_load(ap + 1); \
    } \
}

#define COMPUTE(B, arr) { \
    const char* hiLb = (B) ? hi1 : hi0; \
    const char* loLb = (B) ? lo1 : lo0; \
    const float* e2c = (const float*)((B) ? e2L1 : e2L0); \
    _Pragma("unroll") \
    for (int ks = 0; ks < 4; ks++) { \
        int krel = ks * 32 + kg * 8; \
        i32x4 a0 = arr[2 * ks]; \
        i32x4 a1 = arr[2 * ks + 1]; \
        f32x4 e20 = *(const f32x4*)(e2c + krel); \
        f32x4 e21 = *(const f32x4*)(e2c + krel + 4); \
        float xs[8] = {e20.x, e20.y, e20.z, e20.w, e21.x, e21.y, e21.z, e21.w}; \
        int ms[8] = {a0.x, a0.y, a0.z, a0.w, a1.x, a1.y, a1.z, a1.w}; \
        bf16x8 pf; \
        _Pragma("unroll") \
        for (int i = 0; i < 8; i++) { \
            float x = e1v + xs[i]; \
            x = fmaxf(x, 0.01f * x); \
            x = __expf(x); \
            x = (ms[i] > 0) ? x : 0.0f; \
            pf[i] = (__bf16)x; \
        } \
        int seg = ks * 4 + kg; \
        _Pragma("unroll") \
        for (int n = 0; n < 4; n++) { \
            int c = n * 16 + col; \
            int boff = c * 256 + ((seg ^ (c & 7)) << 4); \
            bf16x8 bhi = __builtin_bit_cast(bf16x8, *(const f32x4*)(hiLb + boff)); \
            bf16x8 blo = __builtin_bit_cast(bf16x8, *(const f32x4*)(loLb + boff)); \
            acc[n] = __builtin_amdgcn_mfma_f32_16x16x32_bf16(pf, bhi, acc[n], 0, 0, 0); \
            acc[n] = __builtin_amdgcn_mfma_f32_16x16x32_bf16(pf, blo, acc[n], 0, 0, 0); \
        } \
        accZ = __builtin_amdgcn_mfma_f32_16x16x32_bf16(pf, onesf, accZ, 0, 0, 0); \
    } \
}

    // prologue: chunk 0 in flight
    STAGE(0, 0);
    ADJP(0, aA);

    #pragma unroll
    for (int jc = 0; jc < NCH; jc += 2) {
        // phase A: prefetch jc+1 into buf1/aB, compute jc from buf0/aA
        STAGE(jc + 1, 1);
        ADJP(jc + 1, aB);
        WAIT18();
        BAR();
        COMPUTE(0, aA);
        BAR();
        // phase B: prefetch jc+2 into buf0/aA, compute jc+1 from buf1/aB
        if (jc + 2 < NCH) {
            STAGE(jc + 2, 0);
            ADJP(jc + 2, aA);
            WAIT18();
        } else {
            WAIT0();
        }
        BAR();
        COMPUTE(1, aB);
        BAR();
    }

    // ---- epilogue: C/D layout col = lane&15, row = (lane>>4)*4 + reg ----
    size_t orow = (size_t)s * BB * NN + (size_t)b * NN + i0 + w * 16 + kg * 4;
    float* accout = accp + orow * CC;
    #pragma unroll
    for (int n = 0; n < 4; n++) {
        #pragma unroll
        for (int r = 0; r < 4; r++) {
            accout[(size_t)r * CC + n * 16 + col] = acc[n][r];
        }
    }
    if (col == 0) {
        #pragma unroll
        for (int r = 0; r < 4; r++) zp[orow + r] = accZ[r];
    }
#undef STAGE
#undef ADJP
#undef COMPUTE
}

// ---------------- Kernel 3: out = sum_s acc[s] / sum_s z[s] ----------------
__global__ __launch_bounds__(256) void k3_final(const float* __restrict__ accp,
        const float* __restrict__ zp, float* __restrict__ out) {
    int idx = blockIdx.x * 256 + threadIdx.x;      // float4 index
    const int TOT4 = BB * NN * CC / 4;             // 262144
    if (idx >= TOT4) return;
    int row = idx >> 4;
    f32x4 s0 = ((const f32x4*)accp)[idx];
    f32x4 s1 = ((const f32x4*)accp)[idx + TOT4];
    float z = zp[row] + zp[row + BB * NN];
    float inv = (z > 0.f) ? (1.0f / z) : 0.f;
    f32x4 o;
    o.x = (s0.x + s1.x) * inv;
    o.y = (s0.y + s1.y) * inv;
    o.z = (s0.z + s1.z) * inv;
    o.w = (s0.w + s1.w) * inv;
    ((f32x4*)out)[idx] = o;
}

extern "C" void kernel_launch(void* const* d_in, const int* in_sizes, int n_in,
                              void* d_out, int out_size, void* d_ws, size_t ws_size,
                              hipStream_t stream) {
    const float* inp = (const float*)d_in[0];
    const int*   adj = (const int*)d_in[1];
    const float* Wm  = (const float*)d_in[2];
    const float* av  = (const float*)d_in[3];
    float* ws = (float*)d_ws;
    float* h    = ws + WS_H;
    float* e1   = ws + WS_E1;
    float* e2   = ws + WS_E2;
    unsigned short* hiT = (unsigned short*)(ws + WS_HT);
    unsigned short* loT = hiT + (size_t)BB * CC * NN;
    float* accp = ws + WS_ACC;
    float* zp   = ws + WS_Z;
    float* out  = (float*)d_out;

    k1_proj<<<BB * NN / 4, 256, 0, stream>>>(inp, Wm, av, h, e1, e2);
    k1b_transpose<<<BB * (NN / 64), 256, 0, stream>>>(h, hiT, loT);
    k2_mfma<<<BB * 32 * JSPLIT, 256, 0, stream>>>(adj, hiT, loT, e1, e2, accp, zp);
    k3_final<<<(BB * NN * CC / 4 + 255) / 256, 256, 0, stream>>>(accp, zp, out);
}

// Round 6
// 60.055 us; speedup vs baseline: 1.0567x; 1.0567x over previous
//
#include <hip/hip_runtime.h>
#include <cstdint>

#define BB 8
#define NN 2048
#define CC 64
#define TI 128           // i-rows per block in k2 (8 waves x 16)
#define JSPLIT 2
#define KRANGE (NN / JSPLIT)   // 1024
#define JCH 128                // j-chunk staged in LDS
#define NCH (KRANGE / JCH)     // 8 chunks

typedef __attribute__((ext_vector_type(8))) __bf16 bf16x8;
typedef __attribute__((ext_vector_type(4))) float f32x4;
typedef __attribute__((ext_vector_type(4))) unsigned int u32x4;
typedef __attribute__((ext_vector_type(4))) int i32x4;

// ws layout (in floats):
static const size_t WS_H   = 0;                                  // B*N*C
static const size_t WS_E1  = WS_H  + (size_t)BB*NN*CC;           // B*N
static const size_t WS_E2  = WS_E1 + (size_t)BB*NN;              // B*N
static const size_t WS_HT  = WS_E2 + (size_t)BB*NN;              // hiT+loT bf16
static const size_t WS_ACC = WS_HT + (size_t)BB*CC*NN;           // JSPLIT*B*N*C floats
static const size_t WS_Z   = WS_ACC + (size_t)JSPLIT*BB*NN*CC;   // JSPLIT*B*N

// async global->LDS, 16B; LDS dest = wave-uniform base + lane*16
#define GL16(g, l) __builtin_amdgcn_global_load_lds( \
    (const __attribute__((address_space(1))) void*)(g), \
    (__attribute__((address_space(3))) void*)(uint32_t)(uintptr_t)(l), 16, 0, 0)
#define WAIT12() asm volatile("s_waitcnt vmcnt(12)" ::: "memory")
#define WAIT0()  asm volatile("s_waitcnt vmcnt(0)" ::: "memory")
#define BAR()    __builtin_amdgcn_s_barrier()

// ---------------- Kernel 1: h = inp @ W ; e1 = h@a1 ; e2 = h@a2 ----------------
__global__ __launch_bounds__(256) void k1_proj(const float* __restrict__ inp,
        const float* __restrict__ Wm, const float* __restrict__ av,
        float* __restrict__ h, float* __restrict__ e1, float* __restrict__ e2) {
    __shared__ float inp_lds[256];
    int t = threadIdx.x;
    size_t base = (size_t)blockIdx.x * 256;
    inp_lds[t] = inp[base + t];
    __syncthreads();
    int r = t >> 6;
    int c = t & 63;
    const float* irow = &inp_lds[r * 64];
    float acc = 0.f;
    #pragma unroll
    for (int k = 0; k < 64; k++) acc = fmaf(irow[k], Wm[k * 64 + c], acc);
    size_t row = (size_t)blockIdx.x * 4 + r;
    h[row * 64 + c] = acc;
    float v1 = acc * av[c];
    float v2 = acc * av[64 + c];
    #pragma unroll
    for (int o = 32; o > 0; o >>= 1) {
        v1 += __shfl_down(v1, o);
        v2 += __shfl_down(v2, o);
    }
    if (c == 0) { e1[row] = v1; e2[row] = v2; }
}

// ---------------- Kernel 1b: transpose h -> bf16 hi/lo, layout [b][c][n] ----------------
__global__ __launch_bounds__(256) void k1b_transpose(const float* __restrict__ h,
        unsigned short* __restrict__ hiT, unsigned short* __restrict__ loT) {
    __shared__ float tile[64][65];
    int t = threadIdx.x;
    int b = blockIdx.x >> 5;           // N/64 = 32 tiles
    int i0 = (blockIdx.x & 31) * 64;
    const float* hb = h + ((size_t)b * NN + i0) * CC;
    #pragma unroll
    for (int q = 0; q < 16; q++) {
        int idx = q * 256 + t;
        tile[idx >> 6][idx & 63] = hb[idx];
    }
    __syncthreads();
    int c = t & 63;
    int rgrp = t >> 6;           // 4 groups of 16 rows
    unsigned int uh[8], ul[8];
    #pragma unroll
    for (int p = 0; p < 8; p++) {
        unsigned int pack_h = 0, pack_l = 0;
        #pragma unroll
        for (int s = 0; s < 2; s++) {
            float v = tile[rgrp * 16 + p * 2 + s][c];
            __bf16 bh = (__bf16)v;
            float fh = (float)bh;
            __bf16 bl = (__bf16)(v - fh);
            unsigned int ubh = (unsigned int)__builtin_bit_cast(unsigned short, bh);
            unsigned int ubl = (unsigned int)__builtin_bit_cast(unsigned short, bl);
            pack_h |= ubh << (16 * s);
            pack_l |= ubl << (16 * s);
        }
        uh[p] = pack_h; ul[p] = pack_l;
    }
    size_t off = ((size_t)b * 64 + c) * NN + i0 + rgrp * 16;   // in ushorts
    u32x4* dh = (u32x4*)(hiT + off);
    u32x4* dl = (u32x4*)(loT + off);
    dh[0] = u32x4{uh[0], uh[1], uh[2], uh[3]};
    dh[1] = u32x4{uh[4], uh[5], uh[6], uh[7]};
    dl[0] = u32x4{ul[0], ul[1], ul[2], ul[3]};
    dl[1] = u32x4{ul[4], ul[5], ul[6], ul[7]};
}

// ---------------- Kernel 2: MFMA attention, TI=128, async double-buffered ----------------
// grid 256: bid = b*32 + tile*2 + s (b in HIGH bits: chunked-XCD-friendly — 32
// consecutive blocks = one batch -> each XCD's h working set is 512 KB, L2-resident).
// 8 waves; wave w owns rows i0 + w*16 .. +15.
__global__ __launch_bounds__(512, 2) void k2_mfma(const int* __restrict__ adj,
        const unsigned short* __restrict__ hiT, const unsigned short* __restrict__ loT,
        const float* __restrict__ e1, const float* __restrict__ e2,
        float* __restrict__ accp, float* __restrict__ zp) {
    __shared__ __align__(16) char smem[4 * 16384 + 4096];
    char* hi0 = smem;              // each 16 KB: 64 rows x 256B (128 bf16), swizzled
    char* lo0 = smem + 16384;
    char* hi1 = smem + 32768;
    char* lo1 = smem + 49152;
    float* e2L = (float*)(smem + 65536);   // full KRANGE slice, 4 KB

    int bid = blockIdx.x;
    int s    = bid & (JSPLIT - 1);
    int tile = (bid >> 1) & 15;
    int b    = bid >> 5;
    int i0 = tile * TI;
    int jbase = s * KRANGE;

    int t = threadIdx.x;
    int w = t >> 6;
    int l = t & 63;
    int col = l & 15;
    int kg  = l >> 4;       // k-group 0..3

    // staging geometry: 8 waves; waves 0-3 stage hi, 4-7 lo; each wave 4 GL16.
    int wlo = w >> 2;
    int ww  = w & 3;
    int cB  = ww * 16 + (l >> 4);     // row for q=0; +4 per q
    int sl  = l & 15;

    const int* adjrow = adj + ((size_t)b * NN + i0 + w * 16 + col) * NN;
    float e1v = e1[(size_t)b * NN + i0 + w * 16 + col];
    const float* e2b = e2 + (size_t)b * NN;
    const unsigned short* hiTb = hiT + (size_t)b * 64 * NN;
    const unsigned short* loTb = loT + (size_t)b * 64 * NN;
    const unsigned short* sTb = wlo ? loTb : hiTb;

    // e2 slice staged ONCE (b-dependent only)
    #pragma unroll
    for (int q = 0; q < 2; q++) e2L[t + q * 512] = e2b[jbase + t + q * 512];
    __syncthreads();

    f32x4 acc[4];
    #pragma unroll
    for (int n = 0; n < 4; n++) acc[n] = f32x4{0.f, 0.f, 0.f, 0.f};
    f32x4 accZ = f32x4{0.f, 0.f, 0.f, 0.f};

    __bf16 onev = (__bf16)1.0f, zerov = (__bf16)0.0f;
    bf16x8 onesf;
    #pragma unroll
    for (int i = 0; i < 8; i++) onesf[i] = (col == 0) ? onev : zerov;

    i32x4 aA[8], aB[8];

#define STAGE(jcN, B) { \
    int j0s = jbase + (jcN) * JCH; \
    char* lb = (wlo ? ((B) ? lo1 : lo0) : ((B) ? hi1 : hi0)) + ww * 4096; \
    _Pragma("unroll") \
    for (int q = 0; q < 4; q++) { \
        int c = cB + q * 4; \
        const unsigned short* src = sTb + (size_t)c * NN + j0s + ((sl ^ (c & 7)) << 3); \
        GL16(src, lb + q * 1024); \
    } \
}

#define ADJP(jcN, arr) { \
    int j0a = jbase + (jcN) * JCH; \
    _Pragma("unroll") \
    for (int ks = 0; ks < 4; ks++) { \
        const i32x4* ap = (const i32x4*)(adjrow + j0a + ks * 32 + kg * 8); \
        arr[2 * ks]     = ap[0]; \
        arr[2 * ks + 1] = ap[1]; \
    } \
}

#define COMPUTE(jcN, B, arr) { \
    const char* hiLb = (B) ? hi1 : hi0; \
    const char* loLb = (B) ? lo1 : lo0; \
    const float* e2c = e2L + (jcN) * JCH; \
    _Pragma("unroll") \
    for (int ks = 0; ks < 4; ks++) { \
        int krel = ks * 32 + kg * 8; \
        i32x4 a0 = arr[2 * ks]; \
        i32x4 a1 = arr[2 * ks + 1]; \
        f32x4 e20 = *(const f32x4*)(e2c + krel); \
        f32x4 e21 = *(const f32x4*)(e2c + krel + 4); \
        float xs[8] = {e20.x, e20.y, e20.z, e20.w, e21.x, e21.y, e21.z, e21.w}; \
        int ms[8] = {a0.x, a0.y, a0.z, a0.w, a1.x, a1.y, a1.z, a1.w}; \
        bf16x8 pf; \
        _Pragma("unroll") \
        for (int i = 0; i < 8; i++) { \
            float x = e1v + xs[i]; \
            x = fmaxf(x, 0.01f * x); \
            x = __expf(x); \
            x = (ms[i] > 0) ? x : 0.0f; \
            pf[i] = (__bf16)x; \
        } \
        int seg = ks * 4 + kg; \
        _Pragma("unroll") \
        for (int n = 0; n < 4; n++) { \
            int c = n * 16 + col; \
            int boff = c * 256 + ((seg ^ (c & 7)) << 4); \
            bf16x8 bhi = __builtin_bit_cast(bf16x8, *(const f32x4*)(hiLb + boff)); \
            bf16x8 blo = __builtin_bit_cast(bf16x8, *(const f32x4*)(loLb + boff)); \
            acc[n] = __builtin_amdgcn_mfma_f32_16x16x32_bf16(pf, bhi, acc[n], 0, 0, 0); \
            acc[n] = __builtin_amdgcn_mfma_f32_16x16x32_bf16(pf, blo, acc[n], 0, 0, 0); \
        } \
        accZ = __builtin_amdgcn_mfma_f32_16x16x32_bf16(pf, onesf, accZ, 0, 0, 0); \
    } \
}

    // prologue: chunk 0 in flight
    STAGE(0, 0);
    ADJP(0, aA);

    #pragma unroll
    for (int jc = 0; jc < NCH; jc += 2) {
        // phase A: prefetch jc+1 into buf1/aB, compute jc from buf0/aA
        STAGE(jc + 1, 1);
        ADJP(jc + 1, aB);
        WAIT12();
        BAR();
        COMPUTE(jc, 0, aA);
        BAR();
        // phase B: prefetch jc+2 into buf0/aA, compute jc+1 from buf1/aB
        if (jc + 2 < NCH) {
            STAGE(jc + 2, 0);
            ADJP(jc + 2, aA);
            WAIT12();
        } else {
            WAIT0();
        }
        BAR();
        COMPUTE(jc + 1, 1, aB);
        BAR();
    }

    // ---- epilogue: C/D layout col = lane&15, row = (lane>>4)*4 + reg ----
    size_t orow = (size_t)s * BB * NN + (size_t)b * NN + i0 + w * 16 + kg * 4;
    float* accout = accp + orow * CC;
    #pragma unroll
    for (int n = 0; n < 4; n++) {
        #pragma unroll
        for (int r = 0; r < 4; r++) {
            accout[(size_t)r * CC + n * 16 + col] = acc[n][r];
        }
    }
    if (col == 0) {
        #pragma unroll
        for (int r = 0; r < 4; r++) zp[orow + r] = accZ[r];
    }
#undef STAGE
#undef ADJP
#undef COMPUTE
}

// ---------------- Kernel 3: out = sum_s acc[s] / sum_s z[s] ----------------
__global__ __launch_bounds__(256) void k3_final(const float* __restrict__ accp,
        const float* __restrict__ zp, float* __restrict__ out) {
    int idx = blockIdx.x * 256 + threadIdx.x;      // float4 index
    const int TOT4 = BB * NN * CC / 4;             // 262144
    if (idx >= TOT4) return;
    int row = idx >> 4;
    f32x4 s0 = ((const f32x4*)accp)[idx];
    f32x4 s1 = ((const f32x4*)accp)[idx + TOT4];
    float z = zp[row] + zp[row + BB * NN];
    float inv = (z > 0.f) ? (1.0f / z) : 0.f;
    f32x4 o;
    o.x = (s0.x + s1.x) * inv;
    o.y = (s0.y + s1.y) * inv;
    o.z = (s0.z + s1.z) * inv;
    o.w = (s0.w + s1.w) * inv;
    ((f32x4*)out)[idx] = o;
}

extern "C" void kernel_launch(void* const* d_in, const int* in_sizes, int n_in,
                              void* d_out, int out_size, void* d_ws, size_t ws_size,
                              hipStream_t stream) {
    const float* inp = (const float*)d_in[0];
    const int*   adj = (const int*)d_in[1];
    const float* Wm  = (const float*)d_in[2];
    const float* av  = (const float*)d_in[3];
    float* ws = (float*)d_ws;
    float* h    = ws + WS_H;
    float* e1   = ws + WS_E1;
    float* e2   = ws + WS_E2;
    unsigned short* hiT = (unsigned short*)(ws + WS_HT);
    unsigned short* loT = hiT + (size_t)BB * CC * NN;
    float* accp = ws + WS_ACC;
    float* zp   = ws + WS_Z;
    float* out  = (float*)d_out;

    k1_proj<<<BB * NN / 4, 256, 0, stream>>>(inp, Wm, av, h, e1, e2);
    k1b_transpose<<<BB * (NN / 64), 256, 0, stream>>>(h, hiT, loT);
    k2_mfma<<<BB * (NN / TI) * JSPLIT, 512, 0, stream>>>(adj, hiT, loT, e1, e2, accp, zp);
    k3_final<<<(BB * NN * CC / 4 + 255) / 256, 256, 0, stream>>>(accp, zp, out);
}

// Round 7
// 53.498 us; speedup vs baseline: 1.1863x; 1.1226x over previous
//
#include <hip/hip_runtime.h>
#include <cstdint>

#define BB 8
#define NN 2048
#define CC 64
#define TI 64            // i-rows per block in k2 (4 waves x 16)
#define JSPLIT 2
#define KRANGE (NN / JSPLIT)   // 1024
#define JCH 128                // j-chunk staged in LDS
#define NCH (KRANGE / JCH)     // 8 chunks

typedef __attribute__((ext_vector_type(8))) __bf16 bf16x8;
typedef __attribute__((ext_vector_type(4))) float f32x4;
typedef __attribute__((ext_vector_type(4))) unsigned int u32x4;
typedef __attribute__((ext_vector_type(4))) int i32x4;

// ws layout (in floats):
static const size_t WS_H   = 0;                                  // B*N*C
static const size_t WS_E1  = WS_H  + (size_t)BB*NN*CC;           // B*N
static const size_t WS_E2  = WS_E1 + (size_t)BB*NN;              // B*N
static const size_t WS_HT  = WS_E2 + (size_t)BB*NN;              // hiT+loT bf16
static const size_t WS_ACC = WS_HT + (size_t)BB*CC*NN;           // JSPLIT*B*N*C floats
static const size_t WS_Z   = WS_ACC + (size_t)JSPLIT*BB*NN*CC;   // JSPLIT*B*N

// async global->LDS, 16B and 4B widths; LDS dest = wave-uniform base + lane*width
#define GL16(g, l) __builtin_amdgcn_global_load_lds( \
    (const __attribute__((address_space(1))) void*)(g), \
    (__attribute__((address_space(3))) void*)(uint32_t)(uintptr_t)(l), 16, 0, 0)
#define GL4(g, l) __builtin_amdgcn_global_load_lds( \
    (const __attribute__((address_space(1))) void*)(g), \
    (__attribute__((address_space(3))) void*)(uint32_t)(uintptr_t)(l), 4, 0, 0)
#define WAIT18() asm volatile("s_waitcnt vmcnt(18)" ::: "memory")
#define WAIT0()  asm volatile("s_waitcnt vmcnt(0)" ::: "memory")
#define BAR()    __builtin_amdgcn_s_barrier()

// ---------------- Kernel 1: h = inp @ W ; e1 = h@a1 ; e2 = h@a2 ----------------
__global__ __launch_bounds__(256) void k1_proj(const float* __restrict__ inp,
        const float* __restrict__ Wm, const float* __restrict__ av,
        float* __restrict__ h, float* __restrict__ e1, float* __restrict__ e2) {
    __shared__ float inp_lds[256];
    int t = threadIdx.x;
    size_t base = (size_t)blockIdx.x * 256;
    inp_lds[t] = inp[base + t];
    __syncthreads();
    int r = t >> 6;
    int c = t & 63;
    const float* irow = &inp_lds[r * 64];
    float acc = 0.f;
    #pragma unroll
    for (int k = 0; k < 64; k++) acc = fmaf(irow[k], Wm[k * 64 + c], acc);
    size_t row = (size_t)blockIdx.x * 4 + r;
    h[row * 64 + c] = acc;
    float v1 = acc * av[c];
    float v2 = acc * av[64 + c];
    #pragma unroll
    for (int o = 32; o > 0; o >>= 1) {
        v1 += __shfl_down(v1, o);
        v2 += __shfl_down(v2, o);
    }
    if (c == 0) { e1[row] = v1; e2[row] = v2; }
}

// ---------------- Kernel 1b: transpose h -> bf16 hi/lo, layout [b][c][n] ----------------
__global__ __launch_bounds__(256) void k1b_transpose(const float* __restrict__ h,
        unsigned short* __restrict__ hiT, unsigned short* __restrict__ loT) {
    __shared__ float tile[64][65];
    int t = threadIdx.x;
    int b = blockIdx.x >> 5;           // N/64 = 32 tiles
    int i0 = (blockIdx.x & 31) * 64;
    const float* hb = h + ((size_t)b * NN + i0) * CC;
    #pragma unroll
    for (int q = 0; q < 16; q++) {
        int idx = q * 256 + t;
        tile[idx >> 6][idx & 63] = hb[idx];
    }
    __syncthreads();
    int c = t & 63;
    int rgrp = t >> 6;           // 4 groups of 16 rows
    unsigned int uh[8], ul[8];
    #pragma unroll
    for (int p = 0; p < 8; p++) {
        unsigned int pack_h = 0, pack_l = 0;
        #pragma unroll
        for (int s = 0; s < 2; s++) {
            float v = tile[rgrp * 16 + p * 2 + s][c];
            __bf16 bh = (__bf16)v;
            float fh = (float)bh;
            __bf16 bl = (__bf16)(v - fh);
            unsigned int ubh = (unsigned int)__builtin_bit_cast(unsigned short, bh);
            unsigned int ubl = (unsigned int)__builtin_bit_cast(unsigned short, bl);
            pack_h |= ubh << (16 * s);
            pack_l |= ubl << (16 * s);
        }
        uh[p] = pack_h; ul[p] = pack_l;
    }
    size_t off = ((size_t)b * 64 + c) * NN + i0 + rgrp * 16;   // in ushorts
    u32x4* dh = (u32x4*)(hiT + off);
    u32x4* dl = (u32x4*)(loT + off);
    dh[0] = u32x4{uh[0], uh[1], uh[2], uh[3]};
    dh[1] = u32x4{uh[4], uh[5], uh[6], uh[7]};
    dl[0] = u32x4{ul[0], ul[1], ul[2], ul[3]};
    dl[1] = u32x4{ul[4], ul[5], ul[6], ul[7]};
}

// ---------------- Kernel 2: MFMA attention, async double-buffered pipeline ----------------
// grid 512: b = bid & 7 -> hardware round-robin dispatch puts all of batch b's
// blocks on XCD b; h working set (hiT[b]+loT[b] = 512 KB) stays L2-resident.
// NO nt-loads on adj (R5 showed they evict adj's LLC residency: +7 us).
__global__ __launch_bounds__(256) void k2_mfma(const int* __restrict__ adj,
        const unsigned short* __restrict__ hiT, const unsigned short* __restrict__ loT,
        const float* __restrict__ e1, const float* __restrict__ e2,
        float* __restrict__ accp, float* __restrict__ zp) {
    __shared__ __align__(16) char smem[2 * 32768 + 2 * 512];
    char* hi0 = smem;              // each 16 KB: 64 rows x 256B (128 bf16), swizzled
    char* lo0 = smem + 16384;
    char* hi1 = smem + 32768;
    char* lo1 = smem + 49152;
    char* e2L0 = smem + 65536;     // 512 B each
    char* e2L1 = smem + 66048;

    int bid = blockIdx.x;
    int b    = bid & 7;
    int rest = bid >> 3;
    int s    = rest & (JSPLIT - 1);
    int tile = rest >> 1;          // 0..31
    int i0 = tile * TI;
    int jbase = s * KRANGE;

    int t = threadIdx.x;
    int w = t >> 6;
    int l = t & 63;
    int col = l & 15;
    int kg  = l >> 4;       // k-group 0..3

    // staging geometry: wave w covers granules [w*512, w*512+512) of 2048
    int wlo = (w >> 1);               // waves 2,3 stage loT
    int cw  = (w & 1) * 32;           // base channel row
    int l4  = l >> 4;
    int sl  = l & 15;
    int wq_off = (w & 1) * 8192;      // byte offset within the 16KB half

    const int* adjrow = adj + ((size_t)b * NN + i0 + w * 16 + col) * NN;
    float e1v = e1[(size_t)b * NN + i0 + w * 16 + col];
    const float* e2b = e2 + (size_t)b * NN;
    const unsigned short* hiTb = hiT + (size_t)b * 64 * NN;
    const unsigned short* loTb = loT + (size_t)b * 64 * NN;
    const unsigned short* sTb = wlo ? loTb : hiTb;

    f32x4 acc[4];
    #pragma unroll
    for (int n = 0; n < 4; n++) acc[n] = f32x4{0.f, 0.f, 0.f, 0.f};
    f32x4 accZ = f32x4{0.f, 0.f, 0.f, 0.f};

    __bf16 onev = (__bf16)1.0f, zerov = (__bf16)0.0f;
    bf16x8 onesf;
    #pragma unroll
    for (int i = 0; i < 8; i++) onesf[i] = (col == 0) ? onev : zerov;

    i32x4 aA[8], aB[8];

#define STAGE(jcN, B) { \
    int j0s = jbase + (jcN) * JCH; \
    char* lb = (wlo ? ((B) ? lo1 : lo0) : ((B) ? hi1 : hi0)) + wq_off; \
    _Pragma("unroll") \
    for (int q = 0; q < 8; q++) { \
        int c = cw + q * 4 + l4; \
        const unsigned short* src = sTb + (size_t)c * NN + j0s + ((sl ^ (c & 7)) << 3); \
        GL16(src, lb + q * 1024); \
    } \
    GL4(e2b + j0s + l, ((B) ? e2L1 : e2L0)); \
    GL4(e2b + j0s + 64 + l, ((B) ? e2L1 : e2L0) + 256); \
}

#define ADJP(jcN, arr) { \
    int j0a = jbase + (jcN) * JCH; \
    _Pragma("unroll") \
    for (int ks = 0; ks < 4; ks++) { \
        const i32x4* ap = (const i32x4*)(adjrow + j0a + ks * 32 + kg * 8); \
        arr[2 * ks]     = ap[0]; \
        arr[2 * ks + 1] = ap[1]; \
    } \
}

#define COMPUTE(B, arr) { \
    const char* hiLb = (B) ? hi1 : hi0; \
    const char* loLb = (B) ? lo1 : lo0; \
    const float* e2c = (const float*)((B) ? e2L1 : e2L0); \
    _Pragma("unroll") \
    for (int ks = 0; ks < 4; ks++) { \
        int krel = ks * 32 + kg * 8; \
        i32x4 a0 = arr[2 * ks]; \
        i32x4 a1 = arr[2 * ks + 1]; \
        f32x4 e20 = *(const f32x4*)(e2c + krel); \
        f32x4 e21 = *(const f32x4*)(e2c + krel + 4); \
        float xs[8] = {e20.x, e20.y, e20.z, e20.w, e21.x, e21.y, e21.z, e21.w}; \
        int ms[8] = {a0.x, a0.y, a0.z, a0.w, a1.x, a1.y, a1.z, a1.w}; \
        bf16x8 pf; \
        _Pragma("unroll") \
        for (int i = 0; i < 8; i++) { \
            float x = e1v + xs[i]; \
            x = fmaxf(x, 0.01f * x); \
            x = __expf(x); \
            x = (ms[i] > 0) ? x : 0.0f; \
            pf[i] = (__bf16)x; \
        } \
        int seg = ks * 4 + kg; \
        _Pragma("unroll") \
        for (int n = 0; n < 4; n++) { \
            int c = n * 16 + col; \
            int boff = c * 256 + ((seg ^ (c & 7)) << 4); \
            bf16x8 bhi = __builtin_bit_cast(bf16x8, *(const f32x4*)(hiLb + boff)); \
            bf16x8 blo = __builtin_bit_cast(bf16x8, *(const f32x4*)(loLb + boff)); \
            acc[n] = __builtin_amdgcn_mfma_f32_16x16x32_bf16(pf, bhi, acc[n], 0, 0, 0); \
            acc[n] = __builtin_amdgcn_mfma_f32_16x16x32_bf16(pf, blo, acc[n], 0, 0, 0); \
        } \
        accZ = __builtin_amdgcn_mfma_f32_16x16x32_bf16(pf, onesf, accZ, 0, 0, 0); \
    } \
}

    // prologue: chunk 0 in flight
    STAGE(0, 0);
    ADJP(0, aA);

    #pragma unroll
    for (int jc = 0; jc < NCH; jc += 2) {
        // phase A: prefetch jc+1 into buf1/aB, compute jc from buf0/aA
        STAGE(jc + 1, 1);
        ADJP(jc + 1, aB);
        WAIT18();
        BAR();
        COMPUTE(0, aA);
        BAR();
        // phase B: prefetch jc+2 into buf0/aA, compute jc+1 from buf1/aB
        if (jc + 2 < NCH) {
            STAGE(jc + 2, 0);
            ADJP(jc + 2, aA);
            WAIT18();
        } else {
            WAIT0();
        }
        BAR();
        COMPUTE(1, aB);
        BAR();
    }

    // ---- epilogue: C/D layout col = lane&15, row = (lane>>4)*4 + reg ----
    size_t orow = (size_t)s * BB * NN + (size_t)b * NN + i0 + w * 16 + kg * 4;
    float* accout = accp + orow * CC;
    #pragma unroll
    for (int n = 0; n < 4; n++) {
        #pragma unroll
        for (int r = 0; r < 4; r++) {
            accout[(size_t)r * CC + n * 16 + col] = acc[n][r];
        }
    }
    if (col == 0) {
        #pragma unroll
        for (int r = 0; r < 4; r++) zp[orow + r] = accZ[r];
    }
#undef STAGE
#undef ADJP
#undef COMPUTE
}

// ---------------- Kernel 3: out = sum_s acc[s] / sum_s z[s] ----------------
__global__ __launch_bounds__(256) void k3_final(const float* __restrict__ accp,
        const float* __restrict__ zp, float* __restrict__ out) {
    int idx = blockIdx.x * 256 + threadIdx.x;      // float4 index
    const int TOT4 = BB * NN * CC / 4;             // 262144
    if (idx >= TOT4) return;
    int row = idx >> 4;
    f32x4 s0 = ((const f32x4*)accp)[idx];
    f32x4 s1 = ((const f32x4*)accp)[idx + TOT4];
    float z = zp[row] + zp[row + BB * NN];
    float inv = (z > 0.f) ? (1.0f / z) : 0.f;
    f32x4 o;
    o.x = (s0.x + s1.x) * inv;
    o.y = (s0.y + s1.y) * inv;
    o.z = (s0.z + s1.z) * inv;
    o.w = (s0.w + s1.w) * inv;
    ((f32x4*)out)[idx] = o;
}

extern "C" void kernel_launch(void* const* d_in, const int* in_sizes, int n_in,
                              void* d_out, int out_size, void* d_ws, size_t ws_size,
                              hipStream_t stream) {
    const float* inp = (const float*)d_in[0];
    const int*   adj = (const int*)d_in[1];
    const float* Wm  = (const float*)d_in[2];
    const float* av  = (const float*)d_in[3];
    float* ws = (float*)d_ws;
    float* h    = ws + WS_H;
    float* e1   = ws + WS_E1;
    float* e2   = ws + WS_E2;
    unsigned short* hiT = (unsigned short*)(ws + WS_HT);
    unsigned short* loT = hiT + (size_t)BB * CC * NN;
    float* accp = ws + WS_ACC;
    float* zp   = ws + WS_Z;
    float* out  = (float*)d_out;

    k1_proj<<<BB * NN / 4, 256, 0, stream>>>(inp, Wm, av, h, e1, e2);
    k1b_transpose<<<BB * (NN / 64), 256, 0, stream>>>(h, hiT, loT);
    k2_mfma<<<BB * 32 * JSPLIT, 256, 0, stream>>>(adj, hiT, loT, e1, e2, accp, zp);
    k3_final<<<(BB * NN * CC / 4 + 255) / 256, 256, 0, stream>>>(accp, zp, out);
}

// Round 8
// 53.222 us; speedup vs baseline: 1.1924x; 1.0052x over previous
//
#include <hip/hip_runtime.h>
#include <cstdint>

#define BB 8
#define NN 2048
#define CC 64
#define TI 64            // i-rows per block (4 waves x 16 per K-half)
#define JCH 128          // j-chunk staged in LDS
#define NCH 8            // chunks per K-half (1024/128)

typedef __attribute__((ext_vector_type(8))) __bf16 bf16x8;
typedef __attribute__((ext_vector_type(4))) float f32x4;
typedef __attribute__((ext_vector_type(4))) unsigned int u32x4;
typedef __attribute__((ext_vector_type(4))) int i32x4;

// ws layout (in floats):
static const size_t WS_H   = 0;                                  // B*N*C
static const size_t WS_E1  = WS_H  + (size_t)BB*NN*CC;           // B*N
static const size_t WS_E2  = WS_E1 + (size_t)BB*NN;              // B*N
static const size_t WS_HT  = WS_E2 + (size_t)BB*NN;              // hiT+loT bf16

// async global->LDS, 16B and 4B widths; LDS dest = wave-uniform base + lane*width
#define GL16(g, l) __builtin_amdgcn_global_load_lds( \
    (const __attribute__((address_space(1))) void*)(g), \
    (__attribute__((address_space(3))) void*)(uint32_t)(uintptr_t)(l), 16, 0, 0)
#define GL4(g, l) __builtin_amdgcn_global_load_lds( \
    (const __attribute__((address_space(1))) void*)(g), \
    (__attribute__((address_space(3))) void*)(uint32_t)(uintptr_t)(l), 4, 0, 0)
#define WAIT18() asm volatile("s_waitcnt vmcnt(18)" ::: "memory")
#define WAIT0()  asm volatile("s_waitcnt vmcnt(0)" ::: "memory")
#define BAR()    __builtin_amdgcn_s_barrier()

// ---------------- Kernel 1: h = inp @ W ; e1 = h@a1 ; e2 = h@a2 ----------------
__global__ __launch_bounds__(256) void k1_proj(const float* __restrict__ inp,
        const float* __restrict__ Wm, const float* __restrict__ av,
        float* __restrict__ h, float* __restrict__ e1, float* __restrict__ e2) {
    __shared__ float inp_lds[256];
    int t = threadIdx.x;
    size_t base = (size_t)blockIdx.x * 256;
    inp_lds[t] = inp[base + t];
    __syncthreads();
    int r = t >> 6;
    int c = t & 63;
    const float* irow = &inp_lds[r * 64];
    float acc = 0.f;
    #pragma unroll
    for (int k = 0; k < 64; k++) acc = fmaf(irow[k], Wm[k * 64 + c], acc);
    size_t row = (size_t)blockIdx.x * 4 + r;
    h[row * 64 + c] = acc;
    float v1 = acc * av[c];
    float v2 = acc * av[64 + c];
    #pragma unroll
    for (int o = 32; o > 0; o >>= 1) {
        v1 += __shfl_down(v1, o);
        v2 += __shfl_down(v2, o);
    }
    if (c == 0) { e1[row] = v1; e2[row] = v2; }
}

// ---------------- Kernel 1b: transpose h -> bf16 hi/lo, layout [b][c][n] ----------------
__global__ __launch_bounds__(256) void k1b_transpose(const float* __restrict__ h,
        unsigned short* __restrict__ hiT, unsigned short* __restrict__ loT) {
    __shared__ float tile[64][65];
    int t = threadIdx.x;
    int b = blockIdx.x >> 5;           // N/64 = 32 tiles
    int i0 = (blockIdx.x & 31) * 64;
    const float* hb = h + ((size_t)b * NN + i0) * CC;
    #pragma unroll
    for (int q = 0; q < 16; q++) {
        int idx = q * 256 + t;
        tile[idx >> 6][idx & 63] = hb[idx];
    }
    __syncthreads();
    int c = t & 63;
    int rgrp = t >> 6;           // 4 groups of 16 rows
    unsigned int uh[8], ul[8];
    #pragma unroll
    for (int p = 0; p < 8; p++) {
        unsigned int pack_h = 0, pack_l = 0;
        #pragma unroll
        for (int s = 0; s < 2; s++) {
            float v = tile[rgrp * 16 + p * 2 + s][c];
            __bf16 bh = (__bf16)v;
            float fh = (float)bh;
            __bf16 bl = (__bf16)(v - fh);
            unsigned int ubh = (unsigned int)__builtin_bit_cast(unsigned short, bh);
            unsigned int ubl = (unsigned int)__builtin_bit_cast(unsigned short, bl);
            pack_h |= ubh << (16 * s);
            pack_l |= ubl << (16 * s);
        }
        uh[p] = pack_h; ul[p] = pack_l;
    }
    size_t off = ((size_t)b * 64 + c) * NN + i0 + rgrp * 16;   // in ushorts
    u32x4* dh = (u32x4*)(hiT + off);
    u32x4* dl = (u32x4*)(loT + off);
    dh[0] = u32x4{uh[0], uh[1], uh[2], uh[3]};
    dh[1] = u32x4{uh[4], uh[5], uh[6], uh[7]};
    dl[0] = u32x4{ul[0], ul[1], ul[2], ul[3]};
    dl[1] = u32x4{ul[4], ul[5], ul[6], ul[7]};
}

// ---------------- Kernel 2: MFMA attention, full-K per block, fused finalize ----------------
// grid 256 @ 512 thr: b = bid & 7 (XCD<->batch affinity), tile = bid >> 3.
// Waves 0-3 (hw=0) process j in [0,1024); waves 4-7 (hw=1) j in [1024,2048),
// each half with its own double-buffered staging set. Epilogue: LDS reduce of the
// two halves + divide by Z + direct write to out. No acc/z global round-trip, no k3.
__global__ __launch_bounds__(512, 1) void k2_mfma(const int* __restrict__ adj,
        const unsigned short* __restrict__ hiT, const unsigned short* __restrict__ loT,
        const float* __restrict__ e1, const float* __restrict__ e2,
        float* __restrict__ out) {
    __shared__ __align__(16) char smem[133120];
    // per-half staging: base hw*65536: hi0 +0, lo0 +16384, hi1 +32768, lo1 +49152
    // e2: 131072 + hw*1024 + B*512  (512 B per buffer)
    // reduce scratch (after loop, reuses nothing live): red at 65536 (16 KB), zred at 81920

    int bid = blockIdx.x;
    int b    = bid & 7;
    int tile = bid >> 3;           // 0..31
    int i0 = tile * TI;

    int t = threadIdx.x;
    int w = t >> 6;
    int hw = w >> 2;               // K-half
    int wl = w & 3;                // wave-in-half
    int l = t & 63;
    int col = l & 15;
    int kg  = l >> 4;              // k-group 0..3
    int jbase = hw * 1024;

    // staging geometry within half: waves wl=2,3 stage loT; cw = (wl&1)*32
    int wlo = wl >> 1;
    int cw  = (wl & 1) * 32;
    int l4  = l >> 4;
    int sl  = l & 15;
    int wq_off = (wl & 1) * 8192;
    int half_off = hw * 65536;

    const int* adjrow = adj + ((size_t)b * NN + i0 + wl * 16 + col) * NN;
    float e1v = e1[(size_t)b * NN + i0 + wl * 16 + col];
    const float* e2b = e2 + (size_t)b * NN;
    const unsigned short* hiTb = hiT + (size_t)b * 64 * NN;
    const unsigned short* loTb = loT + (size_t)b * 64 * NN;
    const unsigned short* sTb = wlo ? loTb : hiTb;

    f32x4 acc[4];
    #pragma unroll
    for (int n = 0; n < 4; n++) acc[n] = f32x4{0.f, 0.f, 0.f, 0.f};
    f32x4 accZ = f32x4{0.f, 0.f, 0.f, 0.f};

    __bf16 onev = (__bf16)1.0f, zerov = (__bf16)0.0f;
    bf16x8 onesf;
    #pragma unroll
    for (int i = 0; i < 8; i++) onesf[i] = (col == 0) ? onev : zerov;

    i32x4 aA[8], aB[8];

#define STAGE(jcN, B) { \
    int j0s = jbase + (jcN) * JCH; \
    char* lb = smem + half_off + (wlo ? 16384 : 0) + ((B) ? 32768 : 0) + wq_off; \
    _Pragma("unroll") \
    for (int q = 0; q < 8; q++) { \
        int c = cw + q * 4 + l4; \
        const unsigned short* src = sTb + (size_t)c * NN + j0s + ((sl ^ (c & 7)) << 3); \
        GL16(src, lb + q * 1024); \
    } \
    char* e2d = smem + 131072 + hw * 1024 + ((B) ? 512 : 0); \
    GL4(e2b + j0s + l, e2d); \
    GL4(e2b + j0s + 64 + l, e2d + 256); \
}

#define ADJP(jcN, arr) { \
    int j0a = jbase + (jcN) * JCH; \
    _Pragma("unroll") \
    for (int ks = 0; ks < 4; ks++) { \
        const i32x4* ap = (const i32x4*)(adjrow + j0a + ks * 32 + kg * 8); \
        arr[2 * ks]     = ap[0]; \
        arr[2 * ks + 1] = ap[1]; \
    } \
}

#define COMPUTE(B, arr) { \
    const char* hiLb = smem + half_off + ((B) ? 32768 : 0); \
    const char* loLb = hiLb + 16384; \
    const float* e2c = (const float*)(smem + 131072 + hw * 1024 + ((B) ? 512 : 0)); \
    _Pragma("unroll") \
    for (int ks = 0; ks < 4; ks++) { \
        int krel = ks * 32 + kg * 8; \
        i32x4 a0 = arr[2 * ks]; \
        i32x4 a1 = arr[2 * ks + 1]; \
        f32x4 e20 = *(const f32x4*)(e2c + krel); \
        f32x4 e21 = *(const f32x4*)(e2c + krel + 4); \
        float xs[8] = {e20.x, e20.y, e20.z, e20.w, e21.x, e21.y, e21.z, e21.w}; \
        int ms[8] = {a0.x, a0.y, a0.z, a0.w, a1.x, a1.y, a1.z, a1.w}; \
        bf16x8 pf; \
        _Pragma("unroll") \
        for (int i = 0; i < 8; i++) { \
            float x = e1v + xs[i]; \
            x = fmaxf(x, 0.01f * x); \
            x = __expf(x); \
            x = (ms[i] > 0) ? x : 0.0f; \
            pf[i] = (__bf16)x; \
        } \
        int seg = ks * 4 + kg; \
        _Pragma("unroll") \
        for (int n = 0; n < 4; n++) { \
            int c = n * 16 + col; \
            int boff = c * 256 + ((seg ^ (c & 7)) << 4); \
            bf16x8 bhi = __builtin_bit_cast(bf16x8, *(const f32x4*)(hiLb + boff)); \
            bf16x8 blo = __builtin_bit_cast(bf16x8, *(const f32x4*)(loLb + boff)); \
            acc[n] = __builtin_amdgcn_mfma_f32_16x16x32_bf16(pf, bhi, acc[n], 0, 0, 0); \
            acc[n] = __builtin_amdgcn_mfma_f32_16x16x32_bf16(pf, blo, acc[n], 0, 0, 0); \
        } \
        accZ = __builtin_amdgcn_mfma_f32_16x16x32_bf16(pf, onesf, accZ, 0, 0, 0); \
    } \
}

    // prologue: chunk 0 in flight
    STAGE(0, 0);
    ADJP(0, aA);

    #pragma unroll
    for (int jc = 0; jc < NCH; jc += 2) {
        STAGE(jc + 1, 1);
        ADJP(jc + 1, aB);
        WAIT18();
        BAR();
        COMPUTE(0, aA);
        BAR();
        if (jc + 2 < NCH) {
            STAGE(jc + 2, 0);
            ADJP(jc + 2, aA);
            WAIT18();
        } else {
            WAIT0();
        }
        BAR();
        COMPUTE(1, aB);
        BAR();
    }

    // ---- epilogue: combine halves in LDS, divide by Z, write out directly ----
    // C/D layout: col = lane&15, row = kg*4 + reg
    float* red  = (float*)(smem + 65536 + wl * 4096);   // [16][64] per wl
    float* zred = (float*)(smem + 81920);               // [64]: zred[wl*16 + row]
    if (hw == 1) {
        #pragma unroll
        for (int n = 0; n < 4; n++)
            #pragma unroll
            for (int r = 0; r < 4; r++)
                red[(kg * 4 + r) * 64 + n * 16 + col] = acc[n][r];
        if (col == 0) {
            #pragma unroll
            for (int r = 0; r < 4; r++) zred[wl * 16 + kg * 4 + r] = accZ[r];
        }
    }
    BAR();
    if (hw == 0 && col == 0) {
        #pragma unroll
        for (int r = 0; r < 4; r++) {
            float zt = accZ[r] + zred[wl * 16 + kg * 4 + r];
            zred[wl * 16 + kg * 4 + r] = (zt > 0.f) ? 1.0f / zt : 0.f;
        }
    }
    BAR();
    if (hw == 0) {
        float* outb = out + ((size_t)b * NN + i0 + wl * 16) * CC;
        #pragma unroll
        for (int r = 0; r < 4; r++) {
            float zi = zred[wl * 16 + kg * 4 + r];
            #pragma unroll
            for (int n = 0; n < 4; n++) {
                float v = (acc[n][r] + red[(kg * 4 + r) * 64 + n * 16 + col]) * zi;
                outb[(size_t)(kg * 4 + r) * CC + n * 16 + col] = v;
            }
        }
    }
#undef STAGE
#undef ADJP
#undef COMPUTE
}

extern "C" void kernel_launch(void* const* d_in, const int* in_sizes, int n_in,
                              void* d_out, int out_size, void* d_ws, size_t ws_size,
                              hipStream_t stream) {
    const float* inp = (const float*)d_in[0];
    const int*   adj = (const int*)d_in[1];
    const float* Wm  = (const float*)d_in[2];
    const float* av  = (const float*)d_in[3];
    float* ws = (float*)d_ws;
    float* h    = ws + WS_H;
    float* e1   = ws + WS_E1;
    float* e2   = ws + WS_E2;
    unsigned short* hiT = (unsigned short*)(ws + WS_HT);
    unsigned short* loT = hiT + (size_t)BB * CC * NN;
    float* out  = (float*)d_out;

    k1_proj<<<BB * NN / 4, 256, 0, stream>>>(inp, Wm, av, h, e1, e2);
    k1b_transpose<<<BB * (NN / 64), 256, 0, stream>>>(h, hiT, loT);
    k2_mfma<<<BB * (NN / TI), 512, 0, stream>>>(adj, hiT, loT, e1, e2, out);
}

// Round 9
// 48.353 us; speedup vs baseline: 1.3125x; 1.1007x over previous
//
#include <hip/hip_runtime.h>
#include <cstdint>

#define BB 8
#define NN 2048
#define CC 64
#define TI 64            // i-rows per block (4 waves x 16 per K-half)
#define JCH 128          // j-chunk staged in LDS
#define NCH 8            // chunks per K-half (1024/128)

typedef __attribute__((ext_vector_type(8))) _Float16 f16x8;
typedef __attribute__((ext_vector_type(4))) float f32x4;
typedef __attribute__((ext_vector_type(4))) unsigned int u32x4;
typedef __attribute__((ext_vector_type(4))) int i32x4;

// ws layout (in floats):
static const size_t WS_H   = 0;                                  // B*N*C
static const size_t WS_E1  = WS_H  + (size_t)BB*NN*CC;           // B*N
static const size_t WS_E2  = WS_E1 + (size_t)BB*NN;              // B*N
static const size_t WS_HT  = WS_E2 + (size_t)BB*NN;              // hT fp16: B*C*N ushorts = B*C*N/2 floats

// async global->LDS, 16B and 4B widths; LDS dest = wave-uniform base + lane*width
#define GL16(g, l) __builtin_amdgcn_global_load_lds( \
    (const __attribute__((address_space(1))) void*)(g), \
    (__attribute__((address_space(3))) void*)(uint32_t)(uintptr_t)(l), 16, 0, 0)
#define GL4(g, l) __builtin_amdgcn_global_load_lds( \
    (const __attribute__((address_space(1))) void*)(g), \
    (__attribute__((address_space(3))) void*)(uint32_t)(uintptr_t)(l), 4, 0, 0)
#define WAIT14() asm volatile("s_waitcnt vmcnt(14)" ::: "memory")
#define WAIT0()  asm volatile("s_waitcnt vmcnt(0)" ::: "memory")
#define BAR()    __builtin_amdgcn_s_barrier()

// ---------------- Kernel 1: h = inp @ W ; e1 = h@a1 ; e2 = h@a2 ----------------
__global__ __launch_bounds__(256) void k1_proj(const float* __restrict__ inp,
        const float* __restrict__ Wm, const float* __restrict__ av,
        float* __restrict__ h, float* __restrict__ e1, float* __restrict__ e2) {
    __shared__ float inp_lds[256];
    int t = threadIdx.x;
    size_t base = (size_t)blockIdx.x * 256;
    inp_lds[t] = inp[base + t];
    __syncthreads();
    int r = t >> 6;
    int c = t & 63;
    const float* irow = &inp_lds[r * 64];
    float acc = 0.f;
    #pragma unroll
    for (int k = 0; k < 64; k++) acc = fmaf(irow[k], Wm[k * 64 + c], acc);
    size_t row = (size_t)blockIdx.x * 4 + r;
    h[row * 64 + c] = acc;
    float v1 = acc * av[c];
    float v2 = acc * av[64 + c];
    #pragma unroll
    for (int o = 32; o > 0; o >>= 1) {
        v1 += __shfl_down(v1, o);
        v2 += __shfl_down(v2, o);
    }
    if (c == 0) { e1[row] = v1; e2[row] = v2; }
}

// ---------------- Kernel 1b: transpose h -> fp16, layout [b][c][n] ----------------
__global__ __launch_bounds__(256) void k1b_transpose(const float* __restrict__ h,
        unsigned short* __restrict__ hT) {
    __shared__ float tile[64][65];
    int t = threadIdx.x;
    int b = blockIdx.x >> 5;           // N/64 = 32 tiles
    int i0 = (blockIdx.x & 31) * 64;
    const float* hb = h + ((size_t)b * NN + i0) * CC;
    #pragma unroll
    for (int q = 0; q < 16; q++) {
        int idx = q * 256 + t;
        tile[idx >> 6][idx & 63] = hb[idx];
    }
    __syncthreads();
    int c = t & 63;
    int rgrp = t >> 6;           // 4 groups of 16 rows
    unsigned int uh[8];
    #pragma unroll
    for (int p = 0; p < 8; p++) {
        unsigned int pack_h = 0;
        #pragma unroll
        for (int s = 0; s < 2; s++) {
            float v = tile[rgrp * 16 + p * 2 + s][c];
            _Float16 fh = (_Float16)v;
            unsigned int u = (unsigned int)__builtin_bit_cast(unsigned short, fh);
            pack_h |= u << (16 * s);
        }
        uh[p] = pack_h;
    }
    size_t off = ((size_t)b * 64 + c) * NN + i0 + rgrp * 16;   // in ushorts
    u32x4* dh = (u32x4*)(hT + off);
    dh[0] = u32x4{uh[0], uh[1], uh[2], uh[3]};
    dh[1] = u32x4{uh[4], uh[5], uh[6], uh[7]};
}

// ---------------- Kernel 2: fp16 MFMA attention, full-K per block, fused finalize ----------------
// grid 256 @ 512 thr: b = bid & 7 (XCD<->batch affinity), tile = bid >> 3.
// Waves 0-3 (hw=0): j in [0,1024); waves 4-7 (hw=1): j in [1024,2048).
// LDS: stage bufs 4 x 16 KB (hw x dbuf) at 0..65536; e2 at 65536 (2 KB);
// reduce red at 67584 (16 KB), zred at 83968 (256 B).
__global__ __launch_bounds__(512, 1) void k2_mfma(const int* __restrict__ adj,
        const unsigned short* __restrict__ hT,
        const float* __restrict__ e1, const float* __restrict__ e2,
        float* __restrict__ out) {
    __shared__ __align__(16) char smem[84224];

    int bid = blockIdx.x;
    int b    = bid & 7;
    int tile = bid >> 3;           // 0..31
    int i0 = tile * TI;

    int t = threadIdx.x;
    int w = t >> 6;
    int hw = w >> 2;               // K-half
    int wl = w & 3;                // wave-in-half
    int l = t & 63;
    int col = l & 15;
    int kg  = l >> 4;              // k-group 0..3
    int jbase = hw * 1024;

    int sl  = l & 15;
    int half_off = hw * 32768;

    const int* adjrow = adj + ((size_t)b * NN + i0 + wl * 16 + col) * NN;
    float e1v = e1[(size_t)b * NN + i0 + wl * 16 + col];
    const float* e2b = e2 + (size_t)b * NN;
    const unsigned short* hTb = hT + (size_t)b * 64 * NN;

    f32x4 acc[4];
    #pragma unroll
    for (int n = 0; n < 4; n++) acc[n] = f32x4{0.f, 0.f, 0.f, 0.f};
    f32x4 accZ = f32x4{0.f, 0.f, 0.f, 0.f};

    _Float16 onev = (_Float16)1.0f, zerov = (_Float16)0.0f;
    f16x8 onesf;
    #pragma unroll
    for (int i = 0; i < 8; i++) onesf[i] = (col == 0) ? onev : zerov;

    i32x4 aA[8], aB[8];

// stage 16 KB chunk: 4 waves x 4 GL16; wave wl covers rows wl*16..+15 (4 rows per inst).
// LDS write is linear (base + lane*16); swizzle is applied on the GLOBAL source so the
// read-side XOR swizzle sees conflict-free data (both-sides-or-neither rule).
#define STAGE(jcN, B) { \
    int j0s = jbase + (jcN) * JCH; \
    char* lb = smem + half_off + ((B) ? 16384 : 0) + wl * 4096; \
    _Pragma("unroll") \
    for (int q = 0; q < 4; q++) { \
        int c = wl * 16 + q * 4 + (l >> 4); \
        const unsigned short* src = hTb + (size_t)c * NN + j0s + ((sl ^ (c & 7)) << 3); \
        GL16(src, lb + q * 1024); \
    } \
    char* e2d = smem + 65536 + hw * 1024 + ((B) ? 512 : 0); \
    GL4(e2b + j0s + l, e2d); \
    GL4(e2b + j0s + 64 + l, e2d + 256); \
}

#define ADJP(jcN, arr) { \
    int j0a = jbase + (jcN) * JCH; \
    _Pragma("unroll") \
    for (int ks = 0; ks < 4; ks++) { \
        const i32x4* ap = (const i32x4*)(adjrow + j0a + ks * 32 + kg * 8); \
        arr[2 * ks]     = ap[0]; \
        arr[2 * ks + 1] = ap[1]; \
    } \
}

#define COMPUTE(B, arr) { \
    const char* hLb = smem + half_off + ((B) ? 16384 : 0); \
    const float* e2c = (const float*)(smem + 65536 + hw * 1024 + ((B) ? 512 : 0)); \
    _Pragma("unroll") \
    for (int ks = 0; ks < 4; ks++) { \
        int krel = ks * 32 + kg * 8; \
        i32x4 a0 = arr[2 * ks]; \
        i32x4 a1 = arr[2 * ks + 1]; \
        f32x4 e20 = *(const f32x4*)(e2c + krel); \
        f32x4 e21 = *(const f32x4*)(e2c + krel + 4); \
        float xs[8] = {e20.x, e20.y, e20.z, e20.w, e21.x, e21.y, e21.z, e21.w}; \
        int ms[8] = {a0.x, a0.y, a0.z, a0.w, a1.x, a1.y, a1.z, a1.w}; \
        f16x8 pf; \
        _Pragma("unroll") \
        for (int i = 0; i < 8; i++) { \
            float x = e1v + xs[i]; \
            x = fmaxf(x, 0.01f * x); \
            x = __expf(x); \
            x = (ms[i] > 0) ? x : 0.0f; \
            pf[i] = (_Float16)x; \
        } \
        int seg = ks * 4 + kg; \
        _Pragma("unroll") \
        for (int n = 0; n < 4; n++) { \
            int c = n * 16 + col; \
            int boff = c * 256 + ((seg ^ (c & 7)) << 4); \
            f16x8 hv = __builtin_bit_cast(f16x8, *(const f32x4*)(hLb + boff)); \
            acc[n] = __builtin_amdgcn_mfma_f32_16x16x32_f16(pf, hv, acc[n], 0, 0, 0); \
        } \
        accZ = __builtin_amdgcn_mfma_f32_16x16x32_f16(pf, onesf, accZ, 0, 0, 0); \
    } \
}

    // prologue: chunk 0 in flight (14 VMEM ops per wave per chunk-phase)
    STAGE(0, 0);
    ADJP(0, aA);

    #pragma unroll
    for (int jc = 0; jc < NCH; jc += 2) {
        STAGE(jc + 1, 1);
        ADJP(jc + 1, aB);
        WAIT14();
        BAR();
        COMPUTE(0, aA);
        BAR();
        if (jc + 2 < NCH) {
            STAGE(jc + 2, 0);
            ADJP(jc + 2, aA);
            WAIT14();
        } else {
            WAIT0();
        }
        BAR();
        COMPUTE(1, aB);
        BAR();
    }

    // ---- epilogue: combine halves in LDS, divide by Z, write out directly ----
    // C/D layout: col = lane&15, row = kg*4 + reg
    float* red  = (float*)(smem + 67584 + wl * 4096);   // [16][64] per wl
    float* zred = (float*)(smem + 83968);               // [64]: zred[wl*16 + row]
    if (hw == 1) {
        #pragma unroll
        for (int n = 0; n < 4; n++)
            #pragma unroll
            for (int r = 0; r < 4; r++)
                red[(kg * 4 + r) * 64 + n * 16 + col] = acc[n][r];
        if (col == 0) {
            #pragma unroll
            for (int r = 0; r < 4; r++) zred[wl * 16 + kg * 4 + r] = accZ[r];
        }
    }
    BAR();
    if (hw == 0 && col == 0) {
        #pragma unroll
        for (int r = 0; r < 4; r++) {
            float zt = accZ[r] + zred[wl * 16 + kg * 4 + r];
            zred[wl * 16 + kg * 4 + r] = (zt > 0.f) ? 1.0f / zt : 0.f;
        }
    }
    BAR();
    if (hw == 0) {
        float* outb = out + ((size_t)b * NN + i0 + wl * 16) * CC;
        #pragma unroll
        for (int r = 0; r < 4; r++) {
            float zi = zred[wl * 16 + kg * 4 + r];
            #pragma unroll
            for (int n = 0; n < 4; n++) {
                float v = (acc[n][r] + red[(kg * 4 + r) * 64 + n * 16 + col]) * zi;
                outb[(size_t)(kg * 4 + r) * CC + n * 16 + col] = v;
            }
        }
    }
#undef STAGE
#undef ADJP
#undef COMPUTE
}

extern "C" void kernel_launch(void* const* d_in, const int* in_sizes, int n_in,
                              void* d_out, int out_size, void* d_ws, size_t ws_size,
                              hipStream_t stream) {
    const float* inp = (const float*)d_in[0];
    const int*   adj = (const int*)d_in[1];
    const float* Wm  = (const float*)d_in[2];
    const float* av  = (const float*)d_in[3];
    float* ws = (float*)d_ws;
    float* h    = ws + WS_H;
    float* e1   = ws + WS_E1;
    float* e2   = ws + WS_E2;
    unsigned short* hT = (unsigned short*)(ws + WS_HT);
    float* out  = (float*)d_out;

    k1_proj<<<BB * NN / 4, 256, 0, stream>>>(inp, Wm, av, h, e1, e2);
    k1b_transpose<<<BB * (NN / 64), 256, 0, stream>>>(h, hT);
    k2_mfma<<<BB * (NN / TI), 512, 0, stream>>>(adj, hT, e1, e2, out);
}

// Round 10
// 44.893 us; speedup vs baseline: 1.4136x; 1.0771x over previous
//
#include <hip/hip_runtime.h>
#include <cstdint>

#define BB 8
#define NN 2048
#define CC 64
#define TI 128           // i-rows per block (8 waves x 16)
#define JSPLIT 2
#define KRANGE (NN / JSPLIT)   // 1024 j per block
#define JCH 128                // adj reg-prefetch chunk
#define NCH (KRANGE / JCH)     // 8

typedef __attribute__((ext_vector_type(8))) _Float16 f16x8;
typedef __attribute__((ext_vector_type(4))) float f32x4;
typedef __attribute__((ext_vector_type(4))) unsigned int u32x4;
typedef __attribute__((ext_vector_type(4))) int i32x4;

// ws layout (in floats):
static const size_t WS_H   = 0;                                  // B*N*C
static const size_t WS_E1  = WS_H  + (size_t)BB*NN*CC;           // B*N
static const size_t WS_E2  = WS_E1 + (size_t)BB*NN;              // B*N
static const size_t WS_HT  = WS_E2 + (size_t)BB*NN;              // hT fp16: B*C*N ushorts
static const size_t WS_ACC = WS_HT + (size_t)BB*CC*NN/2;         // JSPLIT*B*N*C floats
static const size_t WS_Z   = WS_ACC + (size_t)JSPLIT*BB*NN*CC;   // JSPLIT*B*N

#define GL16(g, l) __builtin_amdgcn_global_load_lds( \
    (const __attribute__((address_space(1))) void*)(g), \
    (__attribute__((address_space(3))) void*)(uint32_t)(uintptr_t)(l), 16, 0, 0)
#define GL4(g, l) __builtin_amdgcn_global_load_lds( \
    (const __attribute__((address_space(1))) void*)(g), \
    (__attribute__((address_space(3))) void*)(uint32_t)(uintptr_t)(l), 4, 0, 0)
#define WAIT0()  asm volatile("s_waitcnt vmcnt(0)" ::: "memory")
#define BAR()    __builtin_amdgcn_s_barrier()

// ---------------- Kernel 1: h = inp @ W ; e1 = h@a1 ; e2 = h@a2 ----------------
__global__ __launch_bounds__(256) void k1_proj(const float* __restrict__ inp,
        const float* __restrict__ Wm, const float* __restrict__ av,
        float* __restrict__ h, float* __restrict__ e1, float* __restrict__ e2) {
    __shared__ float inp_lds[256];
    int t = threadIdx.x;
    size_t base = (size_t)blockIdx.x * 256;
    inp_lds[t] = inp[base + t];
    __syncthreads();
    int r = t >> 6;
    int c = t & 63;
    const float* irow = &inp_lds[r * 64];
    float acc = 0.f;
    #pragma unroll
    for (int k = 0; k < 64; k++) acc = fmaf(irow[k], Wm[k * 64 + c], acc);
    size_t row = (size_t)blockIdx.x * 4 + r;
    h[row * 64 + c] = acc;
    float v1 = acc * av[c];
    float v2 = acc * av[64 + c];
    #pragma unroll
    for (int o = 32; o > 0; o >>= 1) {
        v1 += __shfl_down(v1, o);
        v2 += __shfl_down(v2, o);
    }
    if (c == 0) { e1[row] = v1; e2[row] = v2; }
}

// ---------------- Kernel 1b: transpose h -> fp16, layout [b][c][n] ----------------
__global__ __launch_bounds__(256) void k1b_transpose(const float* __restrict__ h,
        unsigned short* __restrict__ hT) {
    __shared__ float tile[64][65];
    int t = threadIdx.x;
    int b = blockIdx.x >> 5;           // N/64 = 32 tiles
    int i0 = (blockIdx.x & 31) * 64;
    const float* hb = h + ((size_t)b * NN + i0) * CC;
    #pragma unroll
    for (int q = 0; q < 16; q++) {
        int idx = q * 256 + t;
        tile[idx >> 6][idx & 63] = hb[idx];
    }
    __syncthreads();
    int c = t & 63;
    int rgrp = t >> 6;           // 4 groups of 16 rows
    unsigned int uh[8];
    #pragma unroll
    for (int p = 0; p < 8; p++) {
        unsigned int pack_h = 0;
        #pragma unroll
        for (int s = 0; s < 2; s++) {
            float v = tile[rgrp * 16 + p * 2 + s][c];
            _Float16 fh = (_Float16)v;
            unsigned int u = (unsigned int)__builtin_bit_cast(unsigned short, fh);
            pack_h |= u << (16 * s);
        }
        uh[p] = pack_h;
    }
    size_t off = ((size_t)b * 64 + c) * NN + i0 + rgrp * 16;   // in ushorts
    u32x4* dh = (u32x4*)(hT + off);
    dh[0] = u32x4{uh[0], uh[1], uh[2], uh[3]};
    dh[1] = u32x4{uh[4], uh[5], uh[6], uh[7]};
}

// ---------------- Kernel 2: fp16 MFMA attention; h-half fully LDS-resident ----------------
// grid 256 @ 512 thr: bid = (tile<<4)|(s<<3)|b; b = bid&7 (XCD<->batch affinity).
// Block owns 128 i-rows (8 waves x 16) x one K-half (1024 j). h-half (64ch x 1024 fp16
// = 128 KB) staged ONCE into LDS, then the j-loop is barrier-free: adj reg-prefetch
// (double-buffered) + exp + MFMA only. Partial acc/Z written to ws; k3 combines.
// LDS rows 2048 B; granule (16B) g at row c stored at slot p=(g&120)|((g^c)&7)
// (involution) -> ds_read_b128 column reads are 2-way-max bank aliased (free).
__global__ __launch_bounds__(512, 1) void k2_mfma(const int* __restrict__ adj,
        const unsigned short* __restrict__ hT,
        const float* __restrict__ e1, const float* __restrict__ e2,
        float* __restrict__ accp, float* __restrict__ zp) {
    __shared__ __align__(16) char smem[135168];   // 128 KB h + 4 KB e2
    float* e2L = (float*)(smem + 131072);

    int bid = blockIdx.x;
    int b    = bid & 7;
    int rest = bid >> 3;
    int s    = rest & 1;
    int tile = rest >> 1;          // 0..15
    int i0 = tile * TI;
    int jbase = s * KRANGE;

    int t = threadIdx.x;
    int w = t >> 6;
    int l = t & 63;
    int col = l & 15;
    int kg  = l >> 4;              // k-group 0..3

    const int* adjrow = adj + ((size_t)b * NN + i0 + w * 16 + col) * NN + jbase;
    float e1v = e1[(size_t)b * NN + i0 + w * 16 + col];
    const float* e2b = e2 + (size_t)b * NN;
    const unsigned short* hTb = hT + (size_t)b * 64 * NN;

    f32x4 acc[4];
    #pragma unroll
    for (int n = 0; n < 4; n++) acc[n] = f32x4{0.f, 0.f, 0.f, 0.f};
    f32x4 accZ = f32x4{0.f, 0.f, 0.f, 0.f};

    _Float16 onev = (_Float16)1.0f, zerov = (_Float16)0.0f;
    f16x8 onesf;
    #pragma unroll
    for (int i = 0; i < 8; i++) onesf[i] = (col == 0) ? onev : zerov;

    i32x4 aA[8], aB[8];

#define ADJP(jcN, arr) { \
    _Pragma("unroll") \
    for (int q = 0; q < 4; q++) { \
        const i32x4* ap = (const i32x4*)(adjrow + (jcN) * JCH + q * 32 + kg * 8); \
        arr[2 * q]     = ap[0]; \
        arr[2 * q + 1] = ap[1]; \
    } \
}

#define COMPUTE(jcN, arr) { \
    _Pragma("unroll") \
    for (int ks4 = 0; ks4 < 4; ks4++) { \
        int ks = (jcN) * 4 + ks4; \
        int krel = ks * 32 + kg * 8; \
        i32x4 a0 = arr[2 * ks4]; \
        i32x4 a1 = arr[2 * ks4 + 1]; \
        f32x4 e20 = *(const f32x4*)(e2L + krel); \
        f32x4 e21 = *(const f32x4*)(e2L + krel + 4); \
        float xs[8] = {e20.x, e20.y, e20.z, e20.w, e21.x, e21.y, e21.z, e21.w}; \
        int ms[8] = {a0.x, a0.y, a0.z, a0.w, a1.x, a1.y, a1.z, a1.w}; \
        f16x8 pf; \
        _Pragma("unroll") \
        for (int i = 0; i < 8; i++) { \
            float x = e1v + xs[i]; \
            x = fmaxf(x, 0.01f * x); \
            x = __expf(x); \
            x = (ms[i] > 0) ? x : 0.0f; \
            pf[i] = (_Float16)x; \
        } \
        int g = ks * 4 + kg; \
        _Pragma("unroll") \
        for (int n = 0; n < 4; n++) { \
            int c = n * 16 + col; \
            int p = (g & 120) | ((g ^ c) & 7); \
            f16x8 hv = __builtin_bit_cast(f16x8, *(const f32x4*)(smem + c * 2048 + p * 16)); \
            acc[n] = __builtin_amdgcn_mfma_f32_16x16x32_f16(pf, hv, acc[n], 0, 0, 0); \
        } \
        accZ = __builtin_amdgcn_mfma_f32_16x16x32_f16(pf, onesf, accZ, 0, 0, 0); \
    } \
}

    // ---- adj chunk 0 prefetch first so its latency overlaps the h staging ----
    ADJP(0, aA);

    // ---- stage h-half (128 KB) once: 16 GL16 per wave, swizzled global source ----
    #pragma unroll
    for (int it = 0; it < 16; it++) {
        int k16 = it * 8 + w;            // half-row index 0..127 (wave-uniform)
        int c   = k16 >> 1;              // LDS row
        int p   = (k16 & 1) * 64 + l;    // physical granule within row
        int g   = (p & 120) | ((p ^ c) & 7);   // logical granule (involution)
        const unsigned short* src = hTb + (size_t)c * NN + jbase + g * 8;
        GL16(src, smem + (size_t)k16 * 1024);
    }
    // ---- stage e2 half-slice (4 KB) once ----
    #pragma unroll
    for (int it = 0; it < 2; it++) {
        GL4(e2b + jbase + it * 512 + w * 64 + l,
            smem + 131072 + (it * 512 + w * 64) * 4);
    }
    WAIT0();
    BAR();

    // ---- barrier-free main loop over 8 adj chunks ----
    #pragma unroll
    for (int jc = 0; jc < NCH; jc += 2) {
        ADJP(jc + 1, aB);
        COMPUTE(jc, aA);
        if (jc + 2 < NCH) ADJP(jc + 2, aA);
        COMPUTE(jc + 1, aB);
    }

    // ---- epilogue: partial acc/Z to ws (C/D layout: col=lane&15, row=kg*4+reg) ----
    size_t orow = (size_t)s * BB * NN + (size_t)b * NN + i0 + w * 16 + kg * 4;
    float* accout = accp + orow * CC;
    #pragma unroll
    for (int n = 0; n < 4; n++) {
        #pragma unroll
        for (int r = 0; r < 4; r++) {
            accout[(size_t)r * CC + n * 16 + col] = acc[n][r];
        }
    }
    if (col == 0) {
        #pragma unroll
        for (int r = 0; r < 4; r++) zp[orow + r] = accZ[r];
    }
#undef ADJP
#undef COMPUTE
}

// ---------------- Kernel 3: out = sum_s acc[s] / sum_s z[s] ----------------
__global__ __launch_bounds__(256) void k3_final(const float* __restrict__ accp,
        const float* __restrict__ zp, float* __restrict__ out) {
    int idx = blockIdx.x * 256 + threadIdx.x;      // float4 index
    const int TOT4 = BB * NN * CC / 4;             // 262144
    if (idx >= TOT4) return;
    int row = idx >> 4;
    f32x4 s0 = ((const f32x4*)accp)[idx];
    f32x4 s1 = ((const f32x4*)accp)[idx + TOT4];
    float z = zp[row] + zp[row + BB * NN];
    float inv = (z > 0.f) ? (1.0f / z) : 0.f;
    f32x4 o;
    o.x = (s0.x + s1.x) * inv;
    o.y = (s0.y + s1.y) * inv;
    o.z = (s0.z + s1.z) * inv;
    o.w = (s0.w + s1.w) * inv;
    ((f32x4*)out)[idx] = o;
}

extern "C" void kernel_launch(void* const* d_in, const int* in_sizes, int n_in,
                              void* d_out, int out_size, void* d_ws, size_t ws_size,
                              hipStream_t stream) {
    const float* inp = (const float*)d_in[0];
    const int*   adj = (const int*)d_in[1];
    const float* Wm  = (const float*)d_in[2];
    const float* av  = (const float*)d_in[3];
    float* ws = (float*)d_ws;
    float* h    = ws + WS_H;
    float* e1   = ws + WS_E1;
    float* e2   = ws + WS_E2;
    unsigned short* hT = (unsigned short*)(ws + WS_HT);
    float* accp = ws + WS_ACC;
    float* zp   = ws + WS_Z;
    float* out  = (float*)d_out;

    k1_proj<<<BB * NN / 4, 256, 0, stream>>>(inp, Wm, av, h, e1, e2);
    k1b_transpose<<<BB * (NN / 64), 256, 0, stream>>>(h, hT);
    k2_mfma<<<BB * (NN / TI) * JSPLIT, 512, 0, stream>>>(adj, hT, e1, e2, accp, zp);
    k3_final<<<(BB * NN * CC / 4 + 255) / 256, 256, 0, stream>>>(accp, zp, out);
}